// Round 1
// 683.440 us; speedup vs baseline: 1.0528x; 1.0528x over previous
//
#include <hip/hip_runtime.h>
#include <hip/hip_bf16.h>

// Problem: B=8, N=1024, C=256, R=16
//   qh = q @ Wq^T + bq ; kh = k @ Wk^T + bk       (B,N,C)
//   scores = qh @ kh^T / 16                        (B,N,N)
//   out[b,r,i,j] = scores[b,i,j] * R_map[i,j,r]    (B,R,N,N) fp32
//
// Stage 1: proj_kernel -> qh,kh as bf16 in d_ws (4 MiB each).
//          16x64 tile per wave (4 c-tiles): X re-read 4x instead of 16x.
// Stage 2: score_mul_kernel -> 64x64 score tile via MFMA, LDS relayout,
//          fused multiply with R_map.
//          - XCD-coherent block remap: the 8 b-blocks sharing one R_map tile
//            sit at stride-8 linear ids => same XCD => tile hits L2 once.
//          - multiply phase: dwordx4 nontemporal stores (1 KiB/instruction,
//            write-once data bypasses L2 allocate/evict round-trip).

typedef float  floatx4 __attribute__((ext_vector_type(4)));
typedef short  shortx8 __attribute__((ext_vector_type(8)));

__device__ __forceinline__ short f2bf(float f) {
    // round-to-nearest-even f32 -> bf16 (inputs are finite; no NaN handling)
    unsigned int u = __builtin_bit_cast(unsigned int, f);
    u += 0x7fffu + ((u >> 16) & 1u);
    return (short)(u >> 16);
}

// ---------------- Stage 1: Q/K projection, fp32 in -> bf16 out ----------------
// grid (512, 4, 2), block 64 (one wave). z=0: Q, z=1: K.
// Tile: 16 rows x 64 cols per wave, K=256 in 8 MFMA steps x 4 col-tiles.
__global__ __launch_bounds__(64) void proj_kernel(
    const float* __restrict__ Xq, const float* __restrict__ Wq, const float* __restrict__ bq,
    const float* __restrict__ Xk, const float* __restrict__ Wk, const float* __restrict__ bk,
    short* __restrict__ qh, short* __restrict__ kh)
{
    const float* X; const float* W; const float* bias; short* outp;
    if (blockIdx.z == 0) { X = Xq; W = Wq; bias = bq; outp = qh; }
    else                 { X = Xk; W = Wk; bias = bk; outp = kh; }

    const int lane  = threadIdx.x;
    const int row16 = lane & 15;
    const int quad  = lane >> 4;
    const int m0 = blockIdx.x * 16;   // row tile in (B*N)=8192
    const int c0 = blockIdx.y * 64;   // col tile in C=256

    const float* xr = X + (size_t)(m0 + row16) * 256 + quad * 8;
    const float* wr = W + (size_t)(c0 + row16) * 256 + quad * 8;

    floatx4 acc[4];
#pragma unroll
    for (int nt = 0; nt < 4; nt++) acc[nt] = floatx4{0.f, 0.f, 0.f, 0.f};

#pragma unroll
    for (int k = 0; k < 256; k += 32) {
        float4 a0 = *(const float4*)(xr + k);
        float4 a1 = *(const float4*)(xr + k + 4);
        shortx8 af = { f2bf(a0.x), f2bf(a0.y), f2bf(a0.z), f2bf(a0.w),
                       f2bf(a1.x), f2bf(a1.y), f2bf(a1.z), f2bf(a1.w) };
#pragma unroll
        for (int nt = 0; nt < 4; nt++) {
            const float* w0 = wr + (size_t)nt * 16 * 256 + k;
            float4 b0 = *(const float4*)(w0);
            float4 b1 = *(const float4*)(w0 + 4);
            shortx8 bf = { f2bf(b0.x), f2bf(b0.y), f2bf(b0.z), f2bf(b0.w),
                           f2bf(b1.x), f2bf(b1.y), f2bf(b1.z), f2bf(b1.w) };
            acc[nt] = __builtin_amdgcn_mfma_f32_16x16x32_bf16(af, bf, acc[nt], 0, 0, 0);
        }
    }

    // C/D layout: col = lane&15 (c within tile), row = quad*4+reg (m)
#pragma unroll
    for (int nt = 0; nt < 4; nt++) {
        const int c = c0 + nt * 16 + row16;
        const float bv = bias[c];
#pragma unroll
        for (int r = 0; r < 4; r++) {
            const int m = m0 + quad * 4 + r;
            outp[(size_t)m * 256 + c] = f2bf(acc[nt][r] + bv);
        }
    }
}

// ---------------- Stage 2: fused QK^T * (1/16) * R_map -> out ----------------
// grid (8, 16, 16) = 2048 blocks of 256 threads (4 waves).
// Block remap: lin = x + 8y + 128z; b = (lin>>3)&7; tile = (lin&7) + 8*(lin>>6).
// => the 8 b-blocks of one (i0,j0) tile are at stride-8 linear ids (same XCD,
//    co-resident) so the 256 KiB R_map tile is fetched into that L2 exactly once.
// Wave w computes score rows [i0+16w, i0+16w+16) x cols [j0, j0+64).
__global__ __launch_bounds__(256) void score_mul_kernel(
    const short* __restrict__ qh, const short* __restrict__ kh,
    const float* __restrict__ Rm, float* __restrict__ out)
{
    const int lin  = blockIdx.x + 8 * (blockIdx.y + 16 * blockIdx.z);  // 0..2047
    const int b    = (lin >> 3) & 7;
    const int tile = (lin & 7) + ((lin >> 6) << 3);                    // 0..255
    const int j0 = (tile & 15) * 64;
    const int i0 = (tile >> 4) * 64;

    const int tid   = threadIdx.x;
    const int wave  = tid >> 6;
    const int lane  = tid & 63;
    const int row16 = lane & 15;
    const int quad  = lane >> 4;

    __shared__ float s_lds[64 * 68];   // stride 68 floats: 16B-aligned rows, conflict-light

    // ---- compute phase: 4 MFMA column-tiles per wave over K=256 ----
    const short* qbase = qh + ((size_t)(b * 1024 + i0 + wave * 16 + row16)) * 256 + quad * 8;
    const short* kbase = kh + ((size_t)(b * 1024 + j0 + row16)) * 256 + quad * 8;

    floatx4 acc[4];
#pragma unroll
    for (int nt = 0; nt < 4; nt++) acc[nt] = floatx4{0.f, 0.f, 0.f, 0.f};

#pragma unroll
    for (int k = 0; k < 256; k += 32) {
        shortx8 af = *(const shortx8*)(qbase + k);
#pragma unroll
        for (int nt = 0; nt < 4; nt++) {
            shortx8 bf = *(const shortx8*)(kbase + (size_t)nt * 16 * 256 + k);
            acc[nt] = __builtin_amdgcn_mfma_f32_16x16x32_bf16(af, bf, acc[nt], 0, 0, 0);
        }
    }

    const float inv = 0.0625f;  // 1/sqrt(256)
#pragma unroll
    for (int nt = 0; nt < 4; nt++) {
#pragma unroll
        for (int r = 0; r < 4; r++) {
            const int il = wave * 16 + quad * 4 + r;   // local i
            const int jl = nt * 16 + row16;            // local j
            s_lds[il * 68 + jl] = acc[nt][r] * inv;
        }
    }
    __syncthreads();

    // ---- multiply phase ----
    // lane layout: j4 = lane&15 -> 4 consecutive j (j = j4*4); rg = lane>>4 -> 4 r's.
    // Per (ii, dr): one dwordx4 nontemporal store per thread; a wave-instruction
    // covers 4 planes x 256B = 1 KiB.
    const int j4 = lane & 15;
    const int rg = lane >> 4;
    const int w  = tid >> 6;
    const size_t NN = (size_t)1024 * 1024;

    float* ob = out + ((size_t)(b * 16 + rg * 4)) * NN + j0 + j4 * 4;

#pragma unroll 2
    for (int ii = 0; ii < 16; ii++) {
        const int il = w * 16 + ii;
        const int i  = i0 + il;
        floatx4 s4 = *(const floatx4*)&s_lds[il * 68 + j4 * 4];
        const float* rp = Rm + ((size_t)i * 1024 + j0 + j4 * 4) * 16 + rg * 4;
        floatx4 q0 = *(const floatx4*)(rp);        // R[i, j+0, r0..r0+3]
        floatx4 q1 = *(const floatx4*)(rp + 16);   // R[i, j+1, ...]
        floatx4 q2 = *(const floatx4*)(rp + 32);   // R[i, j+2, ...]
        floatx4 q3 = *(const floatx4*)(rp + 48);   // R[i, j+3, ...]
        float* op = ob + (size_t)i * 1024;

        floatx4 v0 = { s4[0] * q0[0], s4[1] * q1[0], s4[2] * q2[0], s4[3] * q3[0] };
        __builtin_nontemporal_store(v0, (floatx4*)(op));
        floatx4 v1 = { s4[0] * q0[1], s4[1] * q1[1], s4[2] * q2[1], s4[3] * q3[1] };
        __builtin_nontemporal_store(v1, (floatx4*)(op + NN));
        floatx4 v2 = { s4[0] * q0[2], s4[1] * q1[2], s4[2] * q2[2], s4[3] * q3[2] };
        __builtin_nontemporal_store(v2, (floatx4*)(op + 2 * NN));
        floatx4 v3 = { s4[0] * q0[3], s4[1] * q1[3], s4[2] * q2[3], s4[3] * q3[3] };
        __builtin_nontemporal_store(v3, (floatx4*)(op + 3 * NN));
    }
}

extern "C" void kernel_launch(void* const* d_in, const int* in_sizes, int n_in,
                              void* d_out, int out_size, void* d_ws, size_t ws_size,
                              hipStream_t stream) {
    const float* q   = (const float*)d_in[0];  // (8,1024,256)
    const float* k   = (const float*)d_in[1];  // (8,1024,256)
    const float* Wq  = (const float*)d_in[2];  // (256,256)
    const float* bq  = (const float*)d_in[3];  // (256)
    const float* Wk  = (const float*)d_in[4];  // (256,256)
    const float* bk  = (const float*)d_in[5];  // (256)
    const float* Rm  = (const float*)d_in[6];  // (1024,1024,16)
    float* out = (float*)d_out;                // (8,16,1024,1024)

    short* qh = (short*)d_ws;                         // 8192*256 bf16 = 4 MiB
    short* kh = (short*)d_ws + (size_t)8192 * 256;    // next 4 MiB

    dim3 pgrid(512, 4, 2);
    proj_kernel<<<pgrid, 64, 0, stream>>>(q, Wq, bq, k, Wk, bk, qh, kh);

    dim3 sgrid(8, 16, 16);
    score_mul_kernel<<<sgrid, 256, 0, stream>>>(qh, kh, Rm, out);
}

// Round 2
// 668.119 us; speedup vs baseline: 1.0769x; 1.0229x over previous
//
#include <hip/hip_runtime.h>
#include <hip/hip_bf16.h>

// Problem: B=8, N=1024, C=256, R=16
//   qh = q @ Wq^T + bq ; kh = k @ Wk^T + bk       (B,N,C)
//   scores = qh @ kh^T / 16                        (B,N,N)
//   out[b,r,i,j] = scores[b,i,j] * R_map[i,j,r]    (B,R,N,N) fp32
//
// Stage 1: proj_kernel -> qh,kh as bf16 in d_ws (4 MiB each).
// Stage 2: score_mul_kernel, one block per (b, 16-row i-tile), j spans the
//          FULL 1024 row. Rationale: rounds 0/1 wrote 256 B stripes at 4 KiB
//          stride (j-tile 64 x 16 interleaved planes) and sat at ~1.6 TB/s
//          effective write BW; the harness fill streams 6.3 TB/s with long
//          contiguous runs. Full-row tiles make every wave-store 1 KiB
//          contiguous and each (b,r) plane receive 16 full 4 KiB rows
//          (64 KiB contiguous) per block -> DRAM page-friendly streaming.
//          Grid (64,8): linear id = itile + 64*b, XCD = itile%8, so all 8
//          b-sharers of an R_map i-slice run concurrently on one XCD
//          (512 blocks = 2/CU, all resident) -> R_map HBM fetch = 64 MiB once.

typedef float  floatx4 __attribute__((ext_vector_type(4)));
typedef short  shortx8 __attribute__((ext_vector_type(8)));

__device__ __forceinline__ short f2bf(float f) {
    // round-to-nearest-even f32 -> bf16 (inputs are finite; no NaN handling)
    unsigned int u = __builtin_bit_cast(unsigned int, f);
    u += 0x7fffu + ((u >> 16) & 1u);
    return (short)(u >> 16);
}

// ---------------- Stage 1: Q/K projection, fp32 in -> bf16 out ----------------
// grid (512, 4, 2), block 64 (one wave). z=0: Q, z=1: K.
// Tile: 16 rows x 64 cols per wave, K=256 in 8 MFMA steps x 4 col-tiles.
__global__ __launch_bounds__(64) void proj_kernel(
    const float* __restrict__ Xq, const float* __restrict__ Wq, const float* __restrict__ bq,
    const float* __restrict__ Xk, const float* __restrict__ Wk, const float* __restrict__ bk,
    short* __restrict__ qh, short* __restrict__ kh)
{
    const float* X; const float* W; const float* bias; short* outp;
    if (blockIdx.z == 0) { X = Xq; W = Wq; bias = bq; outp = qh; }
    else                 { X = Xk; W = Wk; bias = bk; outp = kh; }

    const int lane  = threadIdx.x;
    const int row16 = lane & 15;
    const int quad  = lane >> 4;
    const int m0 = blockIdx.x * 16;   // row tile in (B*N)=8192
    const int c0 = blockIdx.y * 64;   // col tile in C=256

    const float* xr = X + (size_t)(m0 + row16) * 256 + quad * 8;
    const float* wr = W + (size_t)(c0 + row16) * 256 + quad * 8;

    floatx4 acc[4];
#pragma unroll
    for (int nt = 0; nt < 4; nt++) acc[nt] = floatx4{0.f, 0.f, 0.f, 0.f};

#pragma unroll
    for (int k = 0; k < 256; k += 32) {
        float4 a0 = *(const float4*)(xr + k);
        float4 a1 = *(const float4*)(xr + k + 4);
        shortx8 af = { f2bf(a0.x), f2bf(a0.y), f2bf(a0.z), f2bf(a0.w),
                       f2bf(a1.x), f2bf(a1.y), f2bf(a1.z), f2bf(a1.w) };
#pragma unroll
        for (int nt = 0; nt < 4; nt++) {
            const float* w0 = wr + (size_t)nt * 16 * 256 + k;
            float4 b0 = *(const float4*)(w0);
            float4 b1 = *(const float4*)(w0 + 4);
            shortx8 bf = { f2bf(b0.x), f2bf(b0.y), f2bf(b0.z), f2bf(b0.w),
                           f2bf(b1.x), f2bf(b1.y), f2bf(b1.z), f2bf(b1.w) };
            acc[nt] = __builtin_amdgcn_mfma_f32_16x16x32_bf16(af, bf, acc[nt], 0, 0, 0);
        }
    }

    // C/D layout: col = lane&15 (c within tile), row = quad*4+reg (m)
#pragma unroll
    for (int nt = 0; nt < 4; nt++) {
        const int c = c0 + nt * 16 + row16;
        const float bv = bias[c];
#pragma unroll
        for (int r = 0; r < 4; r++) {
            const int m = m0 + quad * 4 + r;
            outp[(size_t)m * 256 + c] = f2bf(acc[nt][r] + bv);
        }
    }
}

// ---------------- Stage 2: fused QK^T * (1/16) * R_map -> out ----------------
// grid (64, 8): x = i-tile (16 rows), y = b. block 256 = 4 waves.
// Compute: wave w computes scores[i0..i0+15][w*256 .. w*256+255] (16 MFMA
//          column-tiles, A-fragments preloaded in registers) -> LDS (64 KiB).
// Multiply: wave w owns j chunk [w*256, w*256+256); lane owns 4 consecutive j.
//          Per i-row: load R[i, j..j+3, 0..15] (16 dwordx4 along r), transpose
//          in registers, emit 16 nontemporal dwordx4 stores (one per plane),
//          each wave-instruction 1 KiB contiguous; the 4 waves together
//          complete full 4 KiB output rows.
__global__ __launch_bounds__(256) void score_mul_kernel(
    const short* __restrict__ qh, const short* __restrict__ kh,
    const float* __restrict__ Rm, float* __restrict__ out)
{
    const int itile = blockIdx.x;
    const int b     = blockIdx.y;
    const int i0    = itile * 16;

    const int tid   = threadIdx.x;
    const int w     = tid >> 6;
    const int lane  = tid & 63;
    const int row16 = lane & 15;
    const int quad  = lane >> 4;

    __shared__ float s_lds[16 * 1024];   // 64 KiB -> 2 blocks/CU

    // ---- compute phase ----
    const short* qbase = qh + ((size_t)(b * 1024 + i0 + row16)) * 256 + quad * 8;
    shortx8 a[8];
#pragma unroll
    for (int ks = 0; ks < 8; ks++) a[ks] = *(const shortx8*)(qbase + ks * 32);

    const short* kb = kh + ((size_t)(b * 1024 + w * 256 + row16)) * 256 + quad * 8;
    const float inv = 0.0625f;  // 1/sqrt(256)

#pragma unroll 2
    for (int jt = 0; jt < 16; jt++) {
        floatx4 acc = {0.f, 0.f, 0.f, 0.f};
        const short* kr = kb + (size_t)jt * 16 * 256;
#pragma unroll
        for (int ks = 0; ks < 8; ks++) {
            shortx8 bfr = *(const shortx8*)(kr + ks * 32);
            acc = __builtin_amdgcn_mfma_f32_16x16x32_bf16(a[ks], bfr, acc, 0, 0, 0);
        }
        // C/D layout: col = lane&15 (j within tile), row = quad*4+reg (i)
#pragma unroll
        for (int r = 0; r < 4; r++)
            s_lds[(quad * 4 + r) * 1024 + w * 256 + jt * 16 + row16] = acc[r] * inv;
    }
    __syncthreads();

    // ---- multiply phase ----
    const int jc = w * 256 + lane * 4;          // this lane's 4 j columns
    const size_t NN = (size_t)1024 * 1024;
    float* ob = out + (size_t)(b * 16) * NN + jc;

    for (int il = 0; il < 16; il++) {
        const int i = i0 + il;
        floatx4 s4 = *(const floatx4*)&s_lds[il * 1024 + jc];
        const float* rp = Rm + ((size_t)i * 1024 + jc) * 16;

        floatx4 q[4][4];   // q[jo][rg] = R[i, jc+jo, rg*4 .. rg*4+3]
#pragma unroll
        for (int jo = 0; jo < 4; jo++)
#pragma unroll
            for (int rg = 0; rg < 4; rg++)
                q[jo][rg] = *(const floatx4*)(rp + jo * 16 + rg * 4);

        float* op = ob + (size_t)i * 1024;
#pragma unroll
        for (int r = 0; r < 16; r++) {
            const int rg = r >> 2, rs = r & 3;
            floatx4 v = { q[0][rg][rs] * s4[0], q[1][rg][rs] * s4[1],
                          q[2][rg][rs] * s4[2], q[3][rg][rs] * s4[3] };
            __builtin_nontemporal_store(v, (floatx4*)(op + (size_t)r * NN));
        }
    }
}

extern "C" void kernel_launch(void* const* d_in, const int* in_sizes, int n_in,
                              void* d_out, int out_size, void* d_ws, size_t ws_size,
                              hipStream_t stream) {
    const float* q   = (const float*)d_in[0];  // (8,1024,256)
    const float* k   = (const float*)d_in[1];  // (8,1024,256)
    const float* Wq  = (const float*)d_in[2];  // (256,256)
    const float* bq  = (const float*)d_in[3];  // (256)
    const float* Wk  = (const float*)d_in[4];  // (256,256)
    const float* bk  = (const float*)d_in[5];  // (256)
    const float* Rm  = (const float*)d_in[6];  // (1024,1024,16)
    float* out = (float*)d_out;                // (8,16,1024,1024)

    short* qh = (short*)d_ws;                         // 8192*256 bf16 = 4 MiB
    short* kh = (short*)d_ws + (size_t)8192 * 256;    // next 4 MiB

    dim3 pgrid(512, 4, 2);
    proj_kernel<<<pgrid, 64, 0, stream>>>(q, Wq, bq, k, Wk, bk, qh, kh);

    dim3 sgrid(64, 8);
    score_mul_kernel<<<sgrid, 256, 0, stream>>>(qh, kh, Rm, out);
}